// Round 10
// baseline (160.113 us; speedup 1.0000x reference)
//
#include <hip/hip_runtime.h>
#include <hip/hip_bf16.h>

#define N_NODES 4096
#define BATCH 8
#define FEAT 128
#define CAP 256

typedef float v2f __attribute__((ext_vector_type(2)));

__device__ __forceinline__ unsigned short f2bf(float f) {
    unsigned int u = __float_as_uint(f);
    u += 0x7fffu + ((u >> 16) & 1u);   // RNE (finite, non-NaN here)
    return (unsigned short)(u >> 16);
}

// acc[0..3] (float2 pairs) += p * bf16x8(hv)
__device__ __forceinline__ void fma8v(v2f* acc, v2f pp, uint4 hv) {
    unsigned int u;
    v2f t;
    u = hv.x; t[0] = __uint_as_float(u << 16); t[1] = __uint_as_float(u & 0xffff0000u);
    acc[0] += pp * t;
    u = hv.y; t[0] = __uint_as_float(u << 16); t[1] = __uint_as_float(u & 0xffff0000u);
    acc[1] += pp * t;
    u = hv.z; t[0] = __uint_as_float(u << 16); t[1] = __uint_as_float(u & 0xffff0000u);
    acc[2] += pp * t;
    u = hv.w; t[0] = __uint_as_float(u << 16); t[1] = __uint_as_float(u & 0xffff0000u);
    acc[3] += pp * t;
}

// ---------------------------------------------------------------------------
// prep: 1024 homogeneous blocks x 256 threads. Each block sequentially:
//   phase 1: scan 4 rows of A (1 row/wave; 2 bursts of 8 dependency-free
//            float4 loads, then ballot-compact from registers) -> nbr/deg
//   phase 2: gemm 32 rows of x (W staged in 32KB LDS as two 64-k-row
//            chunks, split-float4 bank-free layout) -> bf16 h, fp32 es/ed
// scan & gemm are independent -> no intra-block sync needed between them;
// co-resident blocks at different phase positions overlap HBM and VALU.
// 32KB LDS -> 5 blocks/CU cap; regular (non-cooperative) launch.
// ---------------------------------------------------------------------------
__global__ __launch_bounds__(256) void prep(
        const float* __restrict__ x, const float* __restrict__ A,
        const float* __restrict__ W, const float* __restrict__ a_src,
        const float* __restrict__ a_dst,
        unsigned short* __restrict__ h, float* __restrict__ es,
        float* __restrict__ ed, unsigned short* __restrict__ nbr,
        int* __restrict__ deg) {
    __shared__ float4 Wl4[64 * 32];   // 32 KB: one 64-k-row chunk of W

    int tid = threadIdx.x;
    int lane = tid & 63;
    int w = tid >> 6;
    int bid = blockIdx.x;

    // ================= phase 1: adjacency scan, 1 row per wave ==============
    {
        int row = bid * 4 + w;
        const float4* ar = (const float4*)(A + (size_t)row * N_NODES);
        unsigned short* lst = nbr + (size_t)row * CAP;
        unsigned long long below = (1ull << lane) - 1ull;
        int cnt = 0;
#pragma unroll
        for (int half = 0; half < 2; ++half) {
            float4 v[8];   // 8 independent loads in flight (8KB/wave burst)
#pragma unroll
            for (int c = 0; c < 8; ++c) v[c] = ar[(half * 8 + c) * 64 + lane];
#pragma unroll
            for (int c = 0; c < 8; ++c) {
                bool f0 = v[c].x > 0.f, f1 = v[c].y > 0.f,
                     f2 = v[c].z > 0.f, f3 = v[c].w > 0.f;
                unsigned long long m0 = __ballot(f0), m1 = __ballot(f1),
                                   m2 = __ballot(f2), m3 = __ballot(f3);
                int pos = cnt + (int)__popcll(m0 & below) + (int)__popcll(m1 & below)
                              + (int)__popcll(m2 & below) + (int)__popcll(m3 & below);
                int colb = 4 * ((half * 8 + c) * 64 + lane);
                if (f0) { if (pos < CAP) lst[pos] = (unsigned short)(colb);     ++pos; }
                if (f1) { if (pos < CAP) lst[pos] = (unsigned short)(colb + 1); ++pos; }
                if (f2) { if (pos < CAP) lst[pos] = (unsigned short)(colb + 2); ++pos; }
                if (f3) { if (pos < CAP) lst[pos] = (unsigned short)(colb + 3); ++pos; }
                cnt += (int)__popcll(m0) + (int)__popcll(m1)
                     + (int)__popcll(m2) + (int)__popcll(m3);
            }
        }
        if (lane == 0) deg[row] = cnt < CAP ? cnt : CAP;
    }

    // ================= phase 2: h = x @ W + es/ed ===========================
    {
        int colg = tid & 15;
        int rowg = tid >> 4;            // 0..15
        int c0 = colg * 8;
        int m0 = bid * 32 + rowg * 2;   // 32 rows/block
        const float* xr = x + (size_t)m0 * FEAT;
        const float4* Wv = (const float4*)W;   // (k, j): j=0..31 -> cols 4j..4j+3

        float acc[2][8];
#pragma unroll
        for (int i = 0; i < 2; ++i)
#pragma unroll
            for (int c = 0; c < 8; ++c) acc[i][c] = 0.f;

        for (int kc = 0; kc < 2; ++kc) {    // two 64-row K-chunks of W
            __syncthreads();
            for (int t = tid; t < 64 * 32; t += 256) {
                int k = t >> 5, j = t & 31;
                // split-float4 bank-free layout (R5-verified: 0 conflicts)
                Wl4[k * 32 + ((j & 1) << 4) + (j >> 1)] = Wv[(kc * 64 + k) * 32 + j];
            }
            __syncthreads();
            for (int k = 0; k < 64; k += 4) {
                float4 xv0 = *(const float4*)(xr + kc * 64 + k);
                float4 xv1 = *(const float4*)(xr + FEAT + kc * 64 + k);
#pragma unroll
                for (int kk = 0; kk < 4; ++kk) {
                    float4 wa = Wl4[(k + kk) * 32 + colg];
                    float4 wb = Wl4[(k + kk) * 32 + 16 + colg];
                    float x0 = (&xv0.x)[kk];
                    float x1 = (&xv1.x)[kk];
                    acc[0][0] += x0 * wa.x; acc[0][1] += x0 * wa.y;
                    acc[0][2] += x0 * wa.z; acc[0][3] += x0 * wa.w;
                    acc[0][4] += x0 * wb.x; acc[0][5] += x0 * wb.y;
                    acc[0][6] += x0 * wb.z; acc[0][7] += x0 * wb.w;
                    acc[1][0] += x1 * wa.x; acc[1][1] += x1 * wa.y;
                    acc[1][2] += x1 * wa.z; acc[1][3] += x1 * wa.w;
                    acc[1][4] += x1 * wb.x; acc[1][5] += x1 * wb.y;
                    acc[1][6] += x1 * wb.z; acc[1][7] += x1 * wb.w;
                }
            }
        }

        float as[8], ad[8];
#pragma unroll
        for (int c = 0; c < 8; ++c) { as[c] = a_src[c0 + c]; ad[c] = a_dst[c0 + c]; }

#pragma unroll
        for (int i = 0; i < 2; ++i) {
            uint4 pk;
            pk.x = (unsigned int)f2bf(acc[i][0]) | ((unsigned int)f2bf(acc[i][1]) << 16);
            pk.y = (unsigned int)f2bf(acc[i][2]) | ((unsigned int)f2bf(acc[i][3]) << 16);
            pk.z = (unsigned int)f2bf(acc[i][4]) | ((unsigned int)f2bf(acc[i][5]) << 16);
            pk.w = (unsigned int)f2bf(acc[i][6]) | ((unsigned int)f2bf(acc[i][7]) << 16);
            *(uint4*)(h + (size_t)(m0 + i) * FEAT + c0) = pk;

            float ps = 0.f, pd = 0.f;
#pragma unroll
            for (int c = 0; c < 8; ++c) { ps += acc[i][c] * as[c]; pd += acc[i][c] * ad[c]; }
#pragma unroll
            for (int off = 8; off >= 1; off >>= 1) {
                ps += __shfl_xor(ps, off);
                pd += __shfl_xor(pd, off);
            }
            if (colg == 0) { es[m0 + i] = ps; ed[m0 + i] = pd; }
        }
    }
}

// ---------------------------------------------------------------------------
// aggregate: one wave per (b,i); z/col cached in regs from the max pass.
// Pass 2: 4 groups of 16 lanes x 2 chains = 8 neighbors/iter, 8 bf16 cols
// per lane as one uint4, float2 packed FMA.
// blockIdx&7 = batch -> XCD affinity (h[b] = 1MB, fits per-XCD 4MB L2).
// ---------------------------------------------------------------------------
__global__ __launch_bounds__(256) void aggregate(const unsigned short* __restrict__ h,
                                                 const float* __restrict__ es,
                                                 const float* __restrict__ ed,
                                                 const unsigned short* __restrict__ nbr,
                                                 const int* __restrict__ deg,
                                                 const float* __restrict__ bias,
                                                 float* __restrict__ out) {
    int lane = threadIdx.x & 63;
    int g = lane >> 4;             // neighbor slot within iteration
    int c8 = (lane & 15) * 8;      // this lane's 8 output columns
    int b = blockIdx.x & 7;
    int i = (blockIdx.x >> 3) * 4 + (threadIdx.x >> 6);

    int d = deg[i];
    const unsigned short* lst = nbr + (size_t)i * CAP;
    float esv = es[b * N_NODES + i];
    const float* edb = ed + b * N_NODES;

    float zv0 = -1e30f, zv1 = -1e30f, zv2 = -1e30f, zv3 = -1e30f;
    int cv0 = 0, cv1 = 0, cv2 = 0, cv3 = 0;
    float m = -1e30f;
#define PASS1(c, zz, cc)                                            \
    if (c * 64 < d) {                                               \
        int j = c * 64 + lane;                                      \
        if (j < d) {                                                \
            cc = lst[j];                                            \
            float z0 = esv + edb[cc];                               \
            zz = z0 > 0.f ? z0 : 0.2f * z0;                         \
        }                                                           \
        m = fmaxf(m, zz);                                           \
    }
    PASS1(0, zv0, cv0)
    PASS1(1, zv1, cv1)
    PASS1(2, zv2, cv2)
    PASS1(3, zv3, cv3)
#undef PASS1
#pragma unroll
    for (int off = 32; off >= 1; off >>= 1) m = fmaxf(m, __shfl_xor(m, off));

    const unsigned short* hb = h + (size_t)b * N_NODES * FEAT;
    v2f acc0[4], acc1[4];
#pragma unroll
    for (int k = 0; k < 4; ++k) { acc0[k] = (v2f)(0.f); acc1[k] = (v2f)(0.f); }
    float s = 0.f;
#define PASS2(c, zz, cc)                                                        \
    if (c * 64 < d) {                                                           \
        float p = __expf(zz - m);  /* inactive lanes: exp(-1e30-m)==0 */        \
        s += p;                                                                 \
        int n = d - c * 64; if (n > 64) n = 64;                                 \
        int nn = (n + 7) & ~7;                                                  \
        for (int jj = 0; jj < nn; jj += 8) {                                    \
            int j0 = jj + g, j1 = jj + 4 + g;                                   \
            float p0 = __shfl(p, j0); int cj0 = __shfl(cc, j0);                 \
            float p1 = __shfl(p, j1); int cj1 = __shfl(cc, j1);                 \
            uint4 h0 = *(const uint4*)(hb + (size_t)cj0 * FEAT + c8);           \
            uint4 h1 = *(const uint4*)(hb + (size_t)cj1 * FEAT + c8);           \
            v2f pp0; pp0[0] = p0; pp0[1] = p0;                                  \
            v2f pp1; pp1[0] = p1; pp1[1] = p1;                                  \
            fma8v(acc0, pp0, h0);                                               \
            fma8v(acc1, pp1, h1);                                               \
        }                                                                       \
    }
    PASS2(0, zv0, cv0)
    PASS2(1, zv1, cv1)
    PASS2(2, zv2, cv2)
    PASS2(3, zv3, cv3)
#undef PASS2

#pragma unroll
    for (int off = 32; off >= 1; off >>= 1) s += __shfl_xor(s, off);
    float inv = 1.0f / s;

#pragma unroll
    for (int k = 0; k < 4; ++k) acc0[k] += acc1[k];
#pragma unroll
    for (int k = 0; k < 4; ++k) {
        acc0[k][0] += __shfl_xor(acc0[k][0], 16);
        acc0[k][1] += __shfl_xor(acc0[k][1], 16);
        acc0[k][0] += __shfl_xor(acc0[k][0], 32);
        acc0[k][1] += __shfl_xor(acc0[k][1], 32);
    }

    if (lane < 16) {
        float4 b0 = *(const float4*)(bias + c8);
        float4 b1 = *(const float4*)(bias + c8 + 4);
        float o[8];
        o[0] = acc0[0][0] * inv + b0.x; o[1] = acc0[0][1] * inv + b0.y;
        o[2] = acc0[1][0] * inv + b0.z; o[3] = acc0[1][1] * inv + b0.w;
        o[4] = acc0[2][0] * inv + b1.x; o[5] = acc0[2][1] * inv + b1.y;
        o[6] = acc0[3][0] * inv + b1.z; o[7] = acc0[3][1] * inv + b1.w;
#pragma unroll
        for (int k = 0; k < 8; ++k) o[k] = o[k] > 0.f ? o[k] : 0.3f * o[k];
        float* orow = out + ((size_t)b * N_NODES + i) * FEAT + c8;
        *(float4*)orow = make_float4(o[0], o[1], o[2], o[3]);
        *(float4*)(orow + 4) = make_float4(o[4], o[5], o[6], o[7]);
    }
}

// ---------------------------------------------------------------------------
extern "C" void kernel_launch(void* const* d_in, const int* in_sizes, int n_in,
                              void* d_out, int out_size, void* d_ws, size_t ws_size,
                              hipStream_t stream) {
    const float* x     = (const float*)d_in[0];
    const float* A     = (const float*)d_in[1];
    const float* W     = (const float*)d_in[2];
    const float* bias  = (const float*)d_in[3];
    const float* a_src = (const float*)d_in[4];
    const float* a_dst = (const float*)d_in[5];
    float* out = (float*)d_out;

    // workspace layout (~10.7 MB total)
    char* ws = (char*)d_ws;
    unsigned short* h = (unsigned short*)ws;                  // B*N*C bf16 (8.4 MB)
    float* es = (float*)(h + (size_t)BATCH * N_NODES * FEAT); // B*N floats
    float* ed = es + BATCH * N_NODES;                         // B*N floats
    int*   dg = (int*)(ed + BATCH * N_NODES);                 // N ints
    unsigned short* nb = (unsigned short*)(dg + N_NODES);     // N*CAP ushorts (2 MB)

    hipLaunchKernelGGL(prep, dim3(N_NODES / 4), dim3(256), 0, stream,
                       x, A, W, a_src, a_dst, h, es, ed, nb, dg);
    hipLaunchKernelGGL(aggregate, dim3(BATCH * N_NODES / 4), dim3(256), 0, stream,
                       h, es, ed, nb, dg, bias, out);
}

// Round 11
// 79.524 us; speedup vs baseline: 2.0134x; 2.0134x over previous
//
#include <hip/hip_runtime.h>
#include <hip/hip_bf16.h>

#define N_NODES 4096
#define BATCH 8
#define FEAT 128
#define CAP 256

typedef float v2f __attribute__((ext_vector_type(2)));
typedef short short8 __attribute__((ext_vector_type(8)));
typedef float f32x4 __attribute__((ext_vector_type(4)));

__device__ __forceinline__ unsigned short f2bf(float f) {
    unsigned int u = __float_as_uint(f);
    u += 0x7fffu + ((u >> 16) & 1u);   // RNE (finite, non-NaN here)
    return (unsigned short)(u >> 16);
}

// acc[0..3] (float2 pairs) += p * bf16x8(hv)
__device__ __forceinline__ void fma8v(v2f* acc, v2f pp, uint4 hv) {
    unsigned int u;
    v2f t;
    u = hv.x; t[0] = __uint_as_float(u << 16); t[1] = __uint_as_float(u & 0xffff0000u);
    acc[0] += pp * t;
    u = hv.y; t[0] = __uint_as_float(u << 16); t[1] = __uint_as_float(u & 0xffff0000u);
    acc[1] += pp * t;
    u = hv.z; t[0] = __uint_as_float(u << 16); t[1] = __uint_as_float(u & 0xffff0000u);
    acc[2] += pp * t;
    u = hv.w; t[0] = __uint_as_float(u << 16); t[1] = __uint_as_float(u & 0xffff0000u);
    acc[3] += pp * t;
}

// ---------------------------------------------------------------------------
// K1: A-scan (R8 burst: 16 dependency-free float4 loads then ballot-compact
// from registers) + x -> bf16 cast (coalesced float4 -> ushort4) +
// W -> Wt[n][k] bf16 transpose-cast (block 0 only; 32 KB total).
// ---------------------------------------------------------------------------
__global__ __launch_bounds__(256) void build_cast(const float* __restrict__ A,
                                                  const float* __restrict__ x,
                                                  const float* __restrict__ W,
                                                  unsigned short* __restrict__ nbr,
                                                  int* __restrict__ deg,
                                                  unsigned short* __restrict__ xb,
                                                  unsigned short* __restrict__ Wt) {
    int tid = threadIdx.x;
    int lane = tid & 63;
    int bid = blockIdx.x;

    // ---- scan: one row per wave, register-burst then compact ----
    {
        int row = bid * 4 + (tid >> 6);
        const float4* ar = (const float4*)(A + (size_t)row * N_NODES);
        float4 v[16];
#pragma unroll
        for (int c = 0; c < 16; ++c) v[c] = ar[c * 64 + lane];

        unsigned short* lst = nbr + (size_t)row * CAP;
        unsigned long long below = (1ull << lane) - 1ull;
        int cnt = 0;
#pragma unroll
        for (int c = 0; c < 16; ++c) {
            bool f0 = v[c].x > 0.f, f1 = v[c].y > 0.f, f2 = v[c].z > 0.f, f3 = v[c].w > 0.f;
            unsigned long long m0 = __ballot(f0), m1 = __ballot(f1),
                               m2 = __ballot(f2), m3 = __ballot(f3);
            int pos = cnt + (int)__popcll(m0 & below) + (int)__popcll(m1 & below)
                          + (int)__popcll(m2 & below) + (int)__popcll(m3 & below);
            int colb = 4 * (c * 64 + lane);
            if (f0) { if (pos < CAP) lst[pos] = (unsigned short)(colb);     ++pos; }
            if (f1) { if (pos < CAP) lst[pos] = (unsigned short)(colb + 1); ++pos; }
            if (f2) { if (pos < CAP) lst[pos] = (unsigned short)(colb + 2); ++pos; }
            if (f3) { if (pos < CAP) lst[pos] = (unsigned short)(colb + 3); ++pos; }
            cnt += (int)__popcll(m0) + (int)__popcll(m1)
                 + (int)__popcll(m2) + (int)__popcll(m3);
        }
        if (lane == 0) deg[row] = cnt < CAP ? cnt : CAP;
    }

    // ---- x cast: 1024 float4 per block, fully coalesced ----
    {
        const float4* xv = (const float4*)x;   // 1,048,576 float4 total
#pragma unroll
        for (int it = 0; it < 4; ++it) {
            int f = bid * 1024 + it * 256 + tid;
            float4 v = xv[f];
            ushort4 p;
            p.x = f2bf(v.x); p.y = f2bf(v.y); p.z = f2bf(v.z); p.w = f2bf(v.w);
            ((ushort4*)xb)[f] = p;
        }
    }

    // ---- W transpose-cast (tiny: 16K elems), block 0 only ----
    if (bid == 0) {
        for (int e = tid; e < FEAT * FEAT; e += 256) {
            int k = e >> 7, n = e & 127;
            Wt[n * FEAT + k] = f2bf(W[e]);
        }
    }
}

// ---------------------------------------------------------------------------
// K2: h = xb @ Wt^T via MFMA 16x16x32 bf16 (fp32 accum), fused es/ed.
// 512 blocks x 256 thr (4 waves); wave w owns rows m0+16w..+16, all 128 cols
// (8 n-tiles). Fragment layout (gfx950): A/B elems 0-3 <-> k=(lane>>4)*4+j,
// elems 4-7 <-> k=16+(lane>>4)*4+j, m/n = lane&15; C/D col=lane&15,
// row=(lane>>4)*4+r (m89-verified). b-frags come from Wt (32 KB, L1-hot).
// ---------------------------------------------------------------------------
__global__ __launch_bounds__(256) void gemm_mfma(const unsigned short* __restrict__ xb,
                                                 const unsigned short* __restrict__ Wt,
                                                 const float* __restrict__ a_src,
                                                 const float* __restrict__ a_dst,
                                                 unsigned short* __restrict__ h,
                                                 float* __restrict__ es,
                                                 float* __restrict__ ed) {
    int tid = threadIdx.x;
    int lane = tid & 63;
    int w = tid >> 6;
    int ln = lane & 15;
    int kg = lane >> 4;              // 0..3
    int m0 = blockIdx.x * 64 + w * 16;

    union frag { short8 s; uint u[4]; };

    f32x4 acc[8];
#pragma unroll
    for (int t = 0; t < 8; ++t) acc[t] = (f32x4)(0.f);

    const unsigned short* xrow = xb + (size_t)(m0 + ln) * FEAT;
#pragma unroll
    for (int ks = 0; ks < 4; ++ks) {
        frag af;
        {
            const unsigned short* p = xrow + ks * 32 + kg * 4;
            uint2 lo = *(const uint2*)p;          // k = ks*32 + kg*4 + 0..3
            uint2 hi = *(const uint2*)(p + 16);   // k = ks*32 + 16 + kg*4 + 0..3
            af.u[0] = lo.x; af.u[1] = lo.y; af.u[2] = hi.x; af.u[3] = hi.y;
        }
#pragma unroll
        for (int t = 0; t < 8; ++t) {
            frag bf;
            const unsigned short* q = Wt + (size_t)(t * 16 + ln) * FEAT + ks * 32 + kg * 4;
            uint2 lo = *(const uint2*)q;
            uint2 hi = *(const uint2*)(q + 16);
            bf.u[0] = lo.x; bf.u[1] = lo.y; bf.u[2] = hi.x; bf.u[3] = hi.y;
            acc[t] = __builtin_amdgcn_mfma_f32_16x16x32_bf16(af.s, bf.s, acc[t], 0, 0, 0);
        }
    }

    float as8[8], ad8[8];
#pragma unroll
    for (int t = 0; t < 8; ++t) { as8[t] = a_src[t * 16 + ln]; ad8[t] = a_dst[t * 16 + ln]; }

#pragma unroll
    for (int r = 0; r < 4; ++r) {
        int m = m0 + kg * 4 + r;
        float ps = 0.f, pd = 0.f;
#pragma unroll
        for (int t = 0; t < 8; ++t) {
            float vv = acc[t][r];
            h[(size_t)m * FEAT + t * 16 + ln] = f2bf(vv);
            ps += vv * as8[t];
            pd += vv * ad8[t];
        }
        // reduce over the 16 lanes of this row group (xor stays within group)
#pragma unroll
        for (int off = 8; off >= 1; off >>= 1) {
            ps += __shfl_xor(ps, off);
            pd += __shfl_xor(pd, off);
        }
        if (ln == 0) { es[m] = ps; ed[m] = pd; }
    }
}

// ---------------------------------------------------------------------------
// K3: aggregate (unchanged): one wave per (b,i); reg-cached z/col; 8 nbrs/iter
// (4 groups x 2 chains), 8 bf16 cols/lane as uint4, packed-f32 FMA.
// blockIdx&7 = batch -> XCD/L2 affinity for the 1MB h[b] slice.
// ---------------------------------------------------------------------------
__global__ __launch_bounds__(256) void aggregate(const unsigned short* __restrict__ h,
                                                 const float* __restrict__ es,
                                                 const float* __restrict__ ed,
                                                 const unsigned short* __restrict__ nbr,
                                                 const int* __restrict__ deg,
                                                 const float* __restrict__ bias,
                                                 float* __restrict__ out) {
    int lane = threadIdx.x & 63;
    int g = lane >> 4;
    int c8 = (lane & 15) * 8;
    int b = blockIdx.x & 7;
    int i = (blockIdx.x >> 3) * 4 + (threadIdx.x >> 6);

    int d = deg[i];
    const unsigned short* lst = nbr + (size_t)i * CAP;
    float esv = es[b * N_NODES + i];
    const float* edb = ed + b * N_NODES;

    float zv0 = -1e30f, zv1 = -1e30f, zv2 = -1e30f, zv3 = -1e30f;
    int cv0 = 0, cv1 = 0, cv2 = 0, cv3 = 0;
    float m = -1e30f;
#define PASS1(c, zz, cc)                                            \
    if (c * 64 < d) {                                               \
        int j = c * 64 + lane;                                      \
        if (j < d) {                                                \
            cc = lst[j];                                            \
            float z0 = esv + edb[cc];                               \
            zz = z0 > 0.f ? z0 : 0.2f * z0;                         \
        }                                                           \
        m = fmaxf(m, zz);                                           \
    }
    PASS1(0, zv0, cv0)
    PASS1(1, zv1, cv1)
    PASS1(2, zv2, cv2)
    PASS1(3, zv3, cv3)
#undef PASS1
#pragma unroll
    for (int off = 32; off >= 1; off >>= 1) m = fmaxf(m, __shfl_xor(m, off));

    const unsigned short* hb = h + (size_t)b * N_NODES * FEAT;
    v2f acc0[4], acc1[4];
#pragma unroll
    for (int k = 0; k < 4; ++k) { acc0[k] = (v2f)(0.f); acc1[k] = (v2f)(0.f); }
    float s = 0.f;
#define PASS2(c, zz, cc)                                                        \
    if (c * 64 < d) {                                                           \
        float p = __expf(zz - m);                                               \
        s += p;                                                                 \
        int n = d - c * 64; if (n > 64) n = 64;                                 \
        int nn = (n + 7) & ~7;                                                  \
        for (int jj = 0; jj < nn; jj += 8) {                                    \
            int j0 = jj + g, j1 = jj + 4 + g;                                   \
            float p0 = __shfl(p, j0); int cj0 = __shfl(cc, j0);                 \
            float p1 = __shfl(p, j1); int cj1 = __shfl(cc, j1);                 \
            uint4 h0 = *(const uint4*)(hb + (size_t)cj0 * FEAT + c8);           \
            uint4 h1 = *(const uint4*)(hb + (size_t)cj1 * FEAT + c8);           \
            v2f pp0; pp0[0] = p0; pp0[1] = p0;                                  \
            v2f pp1; pp1[0] = p1; pp1[1] = p1;                                  \
            fma8v(acc0, pp0, h0);                                               \
            fma8v(acc1, pp1, h1);                                               \
        }                                                                       \
    }
    PASS2(0, zv0, cv0)
    PASS2(1, zv1, cv1)
    PASS2(2, zv2, cv2)
    PASS2(3, zv3, cv3)
#undef PASS2

#pragma unroll
    for (int off = 32; off >= 1; off >>= 1) s += __shfl_xor(s, off);
    float inv = 1.0f / s;

#pragma unroll
    for (int k = 0; k < 4; ++k) acc0[k] += acc1[k];
#pragma unroll
    for (int k = 0; k < 4; ++k) {
        acc0[k][0] += __shfl_xor(acc0[k][0], 16);
        acc0[k][1] += __shfl_xor(acc0[k][1], 16);
        acc0[k][0] += __shfl_xor(acc0[k][0], 32);
        acc0[k][1] += __shfl_xor(acc0[k][1], 32);
    }

    if (lane < 16) {
        float4 b0 = *(const float4*)(bias + c8);
        float4 b1 = *(const float4*)(bias + c8 + 4);
        float o[8];
        o[0] = acc0[0][0] * inv + b0.x; o[1] = acc0[0][1] * inv + b0.y;
        o[2] = acc0[1][0] * inv + b0.z; o[3] = acc0[1][1] * inv + b0.w;
        o[4] = acc0[2][0] * inv + b1.x; o[5] = acc0[2][1] * inv + b1.y;
        o[6] = acc0[3][0] * inv + b1.z; o[7] = acc0[3][1] * inv + b1.w;
#pragma unroll
        for (int k = 0; k < 8; ++k) o[k] = o[k] > 0.f ? o[k] : 0.3f * o[k];
        float* orow = out + ((size_t)b * N_NODES + i) * FEAT + c8;
        *(float4*)orow = make_float4(o[0], o[1], o[2], o[3]);
        *(float4*)(orow + 4) = make_float4(o[4], o[5], o[6], o[7]);
    }
}

// ---------------------------------------------------------------------------
extern "C" void kernel_launch(void* const* d_in, const int* in_sizes, int n_in,
                              void* d_out, int out_size, void* d_ws, size_t ws_size,
                              hipStream_t stream) {
    const float* x     = (const float*)d_in[0];
    const float* A     = (const float*)d_in[1];
    const float* W     = (const float*)d_in[2];
    const float* bias  = (const float*)d_in[3];
    const float* a_src = (const float*)d_in[4];
    const float* a_dst = (const float*)d_in[5];
    float* out = (float*)d_out;

    // workspace layout (~19.3 MB)
    char* ws = (char*)d_ws;
    unsigned short* h  = (unsigned short*)ws;                   // B*N*C bf16 (8.39 MB)
    unsigned short* xb = h + (size_t)BATCH * N_NODES * FEAT;    // B*N*F bf16 (8.39 MB)
    float* es = (float*)(xb + (size_t)BATCH * N_NODES * FEAT);  // B*N f32
    float* ed = es + BATCH * N_NODES;                           // B*N f32
    unsigned short* Wt = (unsigned short*)(ed + BATCH * N_NODES); // F*C bf16 (32 KB)
    int* dg = (int*)(Wt + FEAT * FEAT);                         // N ints
    unsigned short* nb = (unsigned short*)(dg + N_NODES);       // N*CAP (2 MB)

    hipLaunchKernelGGL(build_cast, dim3(N_NODES / 4), dim3(256), 0, stream,
                       A, x, W, nb, dg, xb, Wt);
    hipLaunchKernelGGL(gemm_mfma, dim3(BATCH * N_NODES / 64), dim3(256), 0, stream,
                       xb, Wt, a_src, a_dst, h, es, ed);
    hipLaunchKernelGGL(aggregate, dim3(BATCH * N_NODES / 4), dim3(256), 0, stream,
                       h, es, ed, nb, dg, bias, out);
}

// Round 12
// 70.915 us; speedup vs baseline: 2.2578x; 1.1214x over previous
//
#include <hip/hip_runtime.h>
#include <hip/hip_bf16.h>

#define N_NODES 4096
#define BATCH 8
#define FEAT 128
#define CAP 256

typedef float v2f __attribute__((ext_vector_type(2)));
typedef short short8 __attribute__((ext_vector_type(8)));
typedef float f32x4 __attribute__((ext_vector_type(4)));

__device__ __forceinline__ unsigned short f2bf(float f) {
    unsigned int u = __float_as_uint(f);
    u += 0x7fffu + ((u >> 16) & 1u);   // RNE (finite, non-NaN here)
    return (unsigned short)(u >> 16);
}

__device__ __forceinline__ unsigned int pk2bf(float a, float b) {
    return (unsigned int)f2bf(a) | ((unsigned int)f2bf(b) << 16);
}

// acc[0..3] (float2 pairs) += p * bf16x8(hv)
__device__ __forceinline__ void fma8v(v2f* acc, v2f pp, uint4 hv) {
    unsigned int u;
    v2f t;
    u = hv.x; t[0] = __uint_as_float(u << 16); t[1] = __uint_as_float(u & 0xffff0000u);
    acc[0] += pp * t;
    u = hv.y; t[0] = __uint_as_float(u << 16); t[1] = __uint_as_float(u & 0xffff0000u);
    acc[1] += pp * t;
    u = hv.z; t[0] = __uint_as_float(u << 16); t[1] = __uint_as_float(u & 0xffff0000u);
    acc[2] += pp * t;
    u = hv.w; t[0] = __uint_as_float(u << 16); t[1] = __uint_as_float(u & 0xffff0000u);
    acc[3] += pp * t;
}

// ---------------------------------------------------------------------------
// K1: A-scan, one block per row, 512 threads = 8 waves. Wave w scans cols
// [512w, 512w+512): 2 float4/lane (8 VGPRs -> actually kept in flight, unlike
// R11's 16-float4 "burst" that the compiler serialized at VGPR=40). Ballot-
// compact into an LDS segment (scatter hits LDS, not L2), prefix-merge,
// coalesced global list store. 4 blocks/CU x 8 waves = 32 waves/CU -> ~64KB
// in flight per CU >> BW*latency product -> HBM-rate streaming.
// Block 0 additionally transpose-casts W -> Wt[n][k] bf16 (32 KB).
// ---------------------------------------------------------------------------
__global__ __launch_bounds__(512) void scan_k(const float* __restrict__ A,
                                              const float* __restrict__ W,
                                              unsigned short* __restrict__ nbr,
                                              int* __restrict__ deg,
                                              unsigned short* __restrict__ Wt) {
    __shared__ unsigned short seg[8 * 64];
    __shared__ int scnt[8];

    int tid = threadIdx.x;
    int lane = tid & 63;
    int w = tid >> 6;            // 0..7
    int i = blockIdx.x;

    {
        const float4* ar = (const float4*)(A + (size_t)i * N_NODES);
        unsigned long long below = (1ull << lane) - 1ull;
        // two independent loads, both issued before any consumer
        float4 v0 = ar[w * 128 + lane];
        float4 v1 = ar[w * 128 + 64 + lane];
        int cnt = 0;
#define SCAN4(vv, base)                                                         \
        {                                                                       \
            bool f0 = vv.x > 0.f, f1 = vv.y > 0.f, f2 = vv.z > 0.f, f3 = vv.w > 0.f; \
            unsigned long long m0 = __ballot(f0), m1 = __ballot(f1),            \
                               m2 = __ballot(f2), m3 = __ballot(f3);            \
            int pos = cnt + (int)__popcll(m0 & below) + (int)__popcll(m1 & below) \
                          + (int)__popcll(m2 & below) + (int)__popcll(m3 & below); \
            int colb = base;                                                    \
            if (f0) { if (pos < 64) seg[w * 64 + pos] = (unsigned short)(colb);     ++pos; } \
            if (f1) { if (pos < 64) seg[w * 64 + pos] = (unsigned short)(colb + 1); ++pos; } \
            if (f2) { if (pos < 64) seg[w * 64 + pos] = (unsigned short)(colb + 2); ++pos; } \
            if (f3) { if (pos < 64) seg[w * 64 + pos] = (unsigned short)(colb + 3); ++pos; } \
            cnt += (int)__popcll(m0) + (int)__popcll(m1)                        \
                 + (int)__popcll(m2) + (int)__popcll(m3);                       \
        }
        SCAN4(v0, 4 * (w * 128 + lane))
        SCAN4(v1, 4 * (w * 128 + 64 + lane))
#undef SCAN4
        if (lane == 0) scnt[w] = cnt < 64 ? cnt : 64;
    }
    __syncthreads();

    {
        int off = 0, d = 0;
#pragma unroll
        for (int t = 0; t < 8; ++t) {
            int c = scnt[t];
            if (t < w) off += c;
            d += c;
        }
        int cw = scnt[w];
        unsigned short* lst = nbr + (size_t)i * CAP;
        if (lane < cw && off + lane < CAP) lst[off + lane] = seg[w * 64 + lane];
        if (tid == 0) deg[i] = d < CAP ? d : CAP;
    }

    // ---- W transpose-cast (tiny: 16K elems), block 0 only ----
    if (i == 0) {
        for (int e = tid; e < FEAT * FEAT; e += 512) {
            int k = e >> 7, n = e & 127;
            Wt[n * FEAT + k] = f2bf(W[e]);
        }
    }
}

// ---------------------------------------------------------------------------
// K2: h = x @ Wt^T via MFMA 16x16x32 bf16 (fp32 accum), fused es/ed.
// x is read as f32 and cast to bf16 fragments IN-REGISTER (bit-identical to
// the former xb round-trip, minus ~33 MB of traffic). 512 blocks x 256 thr;
// wave w owns rows m0+16w..+16, all 128 cols (8 n-tiles). Fragment layout
// (gfx950, m89-verified): A/B elems 0-3 <-> k=(lane>>4)*4+j, elems 4-7 <->
// k=16+..., m/n = lane&15; C/D col=lane&15, row=(lane>>4)*4+r.
// ---------------------------------------------------------------------------
__global__ __launch_bounds__(256) void gemm_mfma(const float* __restrict__ x,
                                                 const unsigned short* __restrict__ Wt,
                                                 const float* __restrict__ a_src,
                                                 const float* __restrict__ a_dst,
                                                 unsigned short* __restrict__ h,
                                                 float* __restrict__ es,
                                                 float* __restrict__ ed) {
    int tid = threadIdx.x;
    int lane = tid & 63;
    int w = tid >> 6;
    int ln = lane & 15;
    int kg = lane >> 4;              // 0..3
    int m0 = blockIdx.x * 64 + w * 16;

    union frag { short8 s; uint u[4]; };

    f32x4 acc[8];
#pragma unroll
    for (int t = 0; t < 8; ++t) acc[t] = (f32x4)(0.f);

    const float* xrow = x + (size_t)(m0 + ln) * FEAT;
#pragma unroll
    for (int ks = 0; ks < 4; ++ks) {
        frag af;
        {
            const float* p = xrow + ks * 32 + kg * 4;
            float4 lo = *(const float4*)p;          // k = ks*32 + kg*4 + 0..3
            float4 hi = *(const float4*)(p + 16);   // k = ks*32 + 16 + kg*4 + 0..3
            af.u[0] = pk2bf(lo.x, lo.y); af.u[1] = pk2bf(lo.z, lo.w);
            af.u[2] = pk2bf(hi.x, hi.y); af.u[3] = pk2bf(hi.z, hi.w);
        }
#pragma unroll
        for (int t = 0; t < 8; ++t) {
            frag bf;
            const unsigned short* q = Wt + (size_t)(t * 16 + ln) * FEAT + ks * 32 + kg * 4;
            uint2 lo = *(const uint2*)q;
            uint2 hi = *(const uint2*)(q + 16);
            bf.u[0] = lo.x; bf.u[1] = lo.y; bf.u[2] = hi.x; bf.u[3] = hi.y;
            acc[t] = __builtin_amdgcn_mfma_f32_16x16x32_bf16(af.s, bf.s, acc[t], 0, 0, 0);
        }
    }

    float as8[8], ad8[8];
#pragma unroll
    for (int t = 0; t < 8; ++t) { as8[t] = a_src[t * 16 + ln]; ad8[t] = a_dst[t * 16 + ln]; }

#pragma unroll
    for (int r = 0; r < 4; ++r) {
        int m = m0 + kg * 4 + r;
        float ps = 0.f, pd = 0.f;
#pragma unroll
        for (int t = 0; t < 8; ++t) {
            float vv = acc[t][r];
            h[(size_t)m * FEAT + t * 16 + ln] = f2bf(vv);
            ps += vv * as8[t];
            pd += vv * ad8[t];
        }
#pragma unroll
        for (int off = 8; off >= 1; off >>= 1) {
            ps += __shfl_xor(ps, off);
            pd += __shfl_xor(pd, off);
        }
        if (ln == 0) { es[m] = ps; ed[m] = pd; }
    }
}

// ---------------------------------------------------------------------------
// K3: aggregate (unchanged): one wave per (b,i); reg-cached z/col; 8 nbrs/iter
// (4 groups x 2 chains), 8 bf16 cols/lane as uint4, packed-f32 FMA.
// blockIdx&7 = batch -> XCD/L2 affinity for the 1MB h[b] slice.
// ---------------------------------------------------------------------------
__global__ __launch_bounds__(256) void aggregate(const unsigned short* __restrict__ h,
                                                 const float* __restrict__ es,
                                                 const float* __restrict__ ed,
                                                 const unsigned short* __restrict__ nbr,
                                                 const int* __restrict__ deg,
                                                 const float* __restrict__ bias,
                                                 float* __restrict__ out) {
    int lane = threadIdx.x & 63;
    int g = lane >> 4;
    int c8 = (lane & 15) * 8;
    int b = blockIdx.x & 7;
    int i = (blockIdx.x >> 3) * 4 + (threadIdx.x >> 6);

    int d = deg[i];
    const unsigned short* lst = nbr + (size_t)i * CAP;
    float esv = es[b * N_NODES + i];
    const float* edb = ed + b * N_NODES;

    float zv0 = -1e30f, zv1 = -1e30f, zv2 = -1e30f, zv3 = -1e30f;
    int cv0 = 0, cv1 = 0, cv2 = 0, cv3 = 0;
    float m = -1e30f;
#define PASS1(c, zz, cc)                                            \
    if (c * 64 < d) {                                               \
        int j = c * 64 + lane;                                      \
        if (j < d) {                                                \
            cc = lst[j];                                            \
            float z0 = esv + edb[cc];                               \
            zz = z0 > 0.f ? z0 : 0.2f * z0;                         \
        }                                                           \
        m = fmaxf(m, zz);                                           \
    }
    PASS1(0, zv0, cv0)
    PASS1(1, zv1, cv1)
    PASS1(2, zv2, cv2)
    PASS1(3, zv3, cv3)
#undef PASS1
#pragma unroll
    for (int off = 32; off >= 1; off >>= 1) m = fmaxf(m, __shfl_xor(m, off));

    const unsigned short* hb = h + (size_t)b * N_NODES * FEAT;
    v2f acc0[4], acc1[4];
#pragma unroll
    for (int k = 0; k < 4; ++k) { acc0[k] = (v2f)(0.f); acc1[k] = (v2f)(0.f); }
    float s = 0.f;
#define PASS2(c, zz, cc)                                                        \
    if (c * 64 < d) {                                                           \
        float p = __expf(zz - m);                                               \
        s += p;                                                                 \
        int n = d - c * 64; if (n > 64) n = 64;                                 \
        int nn = (n + 7) & ~7;                                                  \
        for (int jj = 0; jj < nn; jj += 8) {                                    \
            int j0 = jj + g, j1 = jj + 4 + g;                                   \
            float p0 = __shfl(p, j0); int cj0 = __shfl(cc, j0);                 \
            float p1 = __shfl(p, j1); int cj1 = __shfl(cc, j1);                 \
            uint4 h0 = *(const uint4*)(hb + (size_t)cj0 * FEAT + c8);           \
            uint4 h1 = *(const uint4*)(hb + (size_t)cj1 * FEAT + c8);           \
            v2f pp0; pp0[0] = p0; pp0[1] = p0;                                  \
            v2f pp1; pp1[0] = p1; pp1[1] = p1;                                  \
            fma8v(acc0, pp0, h0);                                               \
            fma8v(acc1, pp1, h1);                                               \
        }                                                                       \
    }
    PASS2(0, zv0, cv0)
    PASS2(1, zv1, cv1)
    PASS2(2, zv2, cv2)
    PASS2(3, zv3, cv3)
#undef PASS2

#pragma unroll
    for (int off = 32; off >= 1; off >>= 1) s += __shfl_xor(s, off);
    float inv = 1.0f / s;

#pragma unroll
    for (int k = 0; k < 4; ++k) acc0[k] += acc1[k];
#pragma unroll
    for (int k = 0; k < 4; ++k) {
        acc0[k][0] += __shfl_xor(acc0[k][0], 16);
        acc0[k][1] += __shfl_xor(acc0[k][1], 16);
        acc0[k][0] += __shfl_xor(acc0[k][0], 32);
        acc0[k][1] += __shfl_xor(acc0[k][1], 32);
    }

    if (lane < 16) {
        float4 b0 = *(const float4*)(bias + c8);
        float4 b1 = *(const float4*)(bias + c8 + 4);
        float o[8];
        o[0] = acc0[0][0] * inv + b0.x; o[1] = acc0[0][1] * inv + b0.y;
        o[2] = acc0[1][0] * inv + b0.z; o[3] = acc0[1][1] * inv + b0.w;
        o[4] = acc0[2][0] * inv + b1.x; o[5] = acc0[2][1] * inv + b1.y;
        o[6] = acc0[3][0] * inv + b1.z; o[7] = acc0[3][1] * inv + b1.w;
#pragma unroll
        for (int k = 0; k < 8; ++k) o[k] = o[k] > 0.f ? o[k] : 0.3f * o[k];
        float* orow = out + ((size_t)b * N_NODES + i) * FEAT + c8;
        *(float4*)orow = make_float4(o[0], o[1], o[2], o[3]);
        *(float4*)(orow + 4) = make_float4(o[4], o[5], o[6], o[7]);
    }
}

// ---------------------------------------------------------------------------
extern "C" void kernel_launch(void* const* d_in, const int* in_sizes, int n_in,
                              void* d_out, int out_size, void* d_ws, size_t ws_size,
                              hipStream_t stream) {
    const float* x     = (const float*)d_in[0];
    const float* A     = (const float*)d_in[1];
    const float* W     = (const float*)d_in[2];
    const float* bias  = (const float*)d_in[3];
    const float* a_src = (const float*)d_in[4];
    const float* a_dst = (const float*)d_in[5];
    float* out = (float*)d_out;

    // workspace layout (~10.9 MB)
    char* ws = (char*)d_ws;
    unsigned short* h  = (unsigned short*)ws;                   // B*N*C bf16 (8.39 MB)
    float* es = (float*)(h + (size_t)BATCH * N_NODES * FEAT);   // B*N f32
    float* ed = es + BATCH * N_NODES;                           // B*N f32
    unsigned short* Wt = (unsigned short*)(ed + BATCH * N_NODES); // F*C bf16 (32 KB)
    int* dg = (int*)(Wt + FEAT * FEAT);                         // N ints
    unsigned short* nb = (unsigned short*)(dg + N_NODES);       // N*CAP (2 MB)

    hipLaunchKernelGGL(scan_k, dim3(N_NODES), dim3(512), 0, stream,
                       A, W, nb, dg, Wt);
    hipLaunchKernelGGL(gemm_mfma, dim3(BATCH * N_NODES / 64), dim3(256), 0, stream,
                       x, Wt, a_src, a_dst, h, es, ed);
    hipLaunchKernelGGL(aggregate, dim3(BATCH * N_NODES / 4), dim3(256), 0, stream,
                       h, es, ed, nb, dg, bias, out);
}

// Round 13
// 59.678 us; speedup vs baseline: 2.6829x; 1.1883x over previous
//
#include <hip/hip_runtime.h>
#include <hip/hip_bf16.h>

#define N_NODES 4096
#define BATCH 8
#define FEAT 128
#define CAP 256

typedef float v2f __attribute__((ext_vector_type(2)));
typedef short short8 __attribute__((ext_vector_type(8)));
typedef float f32x4 __attribute__((ext_vector_type(4)));

__device__ __forceinline__ unsigned short f2bf(float f) {
    unsigned int u = __float_as_uint(f);
    u += 0x7fffu + ((u >> 16) & 1u);   // RNE (finite, non-NaN here)
    return (unsigned short)(u >> 16);
}

__device__ __forceinline__ unsigned int pk2bf(float a, float b) {
    return (unsigned int)f2bf(a) | ((unsigned int)f2bf(b) << 16);
}

// acc[0..3] (float2 pairs) += p * bf16x8(hv)
__device__ __forceinline__ void fma8v(v2f* acc, v2f pp, uint4 hv) {
    unsigned int u;
    v2f t;
    u = hv.x; t[0] = __uint_as_float(u << 16); t[1] = __uint_as_float(u & 0xffff0000u);
    acc[0] += pp * t;
    u = hv.y; t[0] = __uint_as_float(u << 16); t[1] = __uint_as_float(u & 0xffff0000u);
    acc[1] += pp * t;
    u = hv.z; t[0] = __uint_as_float(u << 16); t[1] = __uint_as_float(u & 0xffff0000u);
    acc[2] += pp * t;
    u = hv.w; t[0] = __uint_as_float(u << 16); t[1] = __uint_as_float(u & 0xffff0000u);
    acc[3] += pp * t;
}

// ---------------------------------------------------------------------------
// K1: A-scan, one block per row, 512 threads = 8 waves (R12 TLP structure).
// Wave w scans cols [512w, 512w+512): 2 float4/lane, ballot-compact into an
// LDS segment, prefix-merge, coalesced list store. 4 blocks/CU x 8 waves =
// 32 waves/CU. Block 0 also transpose-casts W -> Wt[n][k] bf16.
// ---------------------------------------------------------------------------
__global__ __launch_bounds__(512) void scan_k(const float* __restrict__ A,
                                              const float* __restrict__ W,
                                              unsigned short* __restrict__ nbr,
                                              int* __restrict__ deg,
                                              unsigned short* __restrict__ Wt) {
    __shared__ unsigned short seg[8 * 64];
    __shared__ int scnt[8];

    int tid = threadIdx.x;
    int lane = tid & 63;
    int w = tid >> 6;            // 0..7
    int i = blockIdx.x;

    {
        const float4* ar = (const float4*)(A + (size_t)i * N_NODES);
        unsigned long long below = (1ull << lane) - 1ull;
        float4 v0 = ar[w * 128 + lane];
        float4 v1 = ar[w * 128 + 64 + lane];
        int cnt = 0;
#define SCAN4(vv, base)                                                         \
        {                                                                       \
            bool f0 = vv.x > 0.f, f1 = vv.y > 0.f, f2 = vv.z > 0.f, f3 = vv.w > 0.f; \
            unsigned long long m0 = __ballot(f0), m1 = __ballot(f1),            \
                               m2 = __ballot(f2), m3 = __ballot(f3);            \
            int pos = cnt + (int)__popcll(m0 & below) + (int)__popcll(m1 & below) \
                          + (int)__popcll(m2 & below) + (int)__popcll(m3 & below); \
            int colb = base;                                                    \
            if (f0) { if (pos < 64) seg[w * 64 + pos] = (unsigned short)(colb);     ++pos; } \
            if (f1) { if (pos < 64) seg[w * 64 + pos] = (unsigned short)(colb + 1); ++pos; } \
            if (f2) { if (pos < 64) seg[w * 64 + pos] = (unsigned short)(colb + 2); ++pos; } \
            if (f3) { if (pos < 64) seg[w * 64 + pos] = (unsigned short)(colb + 3); ++pos; } \
            cnt += (int)__popcll(m0) + (int)__popcll(m1)                        \
                 + (int)__popcll(m2) + (int)__popcll(m3);                       \
        }
        SCAN4(v0, 4 * (w * 128 + lane))
        SCAN4(v1, 4 * (w * 128 + 64 + lane))
#undef SCAN4
        if (lane == 0) scnt[w] = cnt < 64 ? cnt : 64;
    }
    __syncthreads();

    {
        int off = 0, d = 0;
#pragma unroll
        for (int t = 0; t < 8; ++t) {
            int c = scnt[t];
            if (t < w) off += c;
            d += c;
        }
        int cw = scnt[w];
        unsigned short* lst = nbr + (size_t)i * CAP;
        if (lane < cw && off + lane < CAP) lst[off + lane] = seg[w * 64 + lane];
        if (tid == 0) deg[i] = d < CAP ? d : CAP;
    }

    if (i == 0) {
        for (int e = tid; e < FEAT * FEAT; e += 512) {
            int k = e >> 7, n = e & 127;
            Wt[n * FEAT + k] = f2bf(W[e]);
        }
    }
}

// ---------------------------------------------------------------------------
// K2: h = x @ Wt^T via MFMA 16x16x32 bf16, CANONICAL LDS-STAGED (fix for the
// ~40us fragment-scatter version): per 64-row block, x-tile is loaded
// coalesced (f32), cast to bf16, and stored to LDS; Wt (32KB, L2-hot) is
// loaded coalesced into LDS. Fragment ds_reads use the XOR swizzle
// kb ^ ((row&7)<<4) -- without it, row stride 256B makes every 16-lane
// fragment read a 16-way bank conflict (G4). row&7 == ln&7 for both
// operands, so the swizzle is one constant per lane.
// Fragment layout (gfx950, m89-verified): A/B elems 0-3 <-> k=(lane>>4)*4+j,
// elems 4-7 <-> k=16+..., m/n = lane&15; C/D col=lane&15, row=(lane>>4)*4+r.
// ---------------------------------------------------------------------------
__global__ __launch_bounds__(256) void gemm_mfma(const float* __restrict__ x,
                                                 const unsigned short* __restrict__ Wt,
                                                 const float* __restrict__ a_src,
                                                 const float* __restrict__ a_dst,
                                                 unsigned short* __restrict__ h,
                                                 float* __restrict__ es,
                                                 float* __restrict__ ed) {
    __shared__ unsigned short xs[64 * FEAT];    // 16 KB, swizzled bf16 x-tile
    __shared__ unsigned short wsh[FEAT * FEAT]; // 32 KB, swizzled bf16 Wt

    int tid = threadIdx.x;
    int lane = tid & 63;
    int w = tid >> 6;
    int ln = lane & 15;
    int kg = lane >> 4;              // 0..3
    int m0 = blockIdx.x * 64;

    // ---- stage Wt[n][k] (bf16) -> wsh, coalesced 8B chunks ----
#pragma unroll
    for (int it = 0; it < 16; ++it) {
        int idx = it * 256 + tid;        // 0..4095
        int n = idx >> 5, c = idx & 31;  // chunk c covers kb = c*8 .. +8
        uint2 v = *(const uint2*)(Wt + (size_t)n * FEAT + c * 4);
        int kb = (c * 8) ^ ((n & 7) << 4);
        *(uint2*)((char*)wsh + n * 256 + kb) = v;
    }
    // ---- stage x rows m0..m0+63 (f32 -> bf16) -> xs, coalesced float4 ----
#pragma unroll
    for (int it = 0; it < 8; ++it) {
        int idx = it * 256 + tid;        // 0..2047
        int r = idx >> 5, c = idx & 31;
        float4 v = *(const float4*)(x + (size_t)(m0 + r) * FEAT + c * 4);
        uint2 p; p.x = pk2bf(v.x, v.y); p.y = pk2bf(v.z, v.w);
        int kb = (c * 8) ^ ((r & 7) << 4);
        *(uint2*)((char*)xs + r * 256 + kb) = p;
    }
    __syncthreads();

    union frag { short8 s; uint u[4]; };
    int sw = (ln & 7) << 4;              // per-lane swizzle constant

    f32x4 acc[8];
#pragma unroll
    for (int t = 0; t < 8; ++t) acc[t] = (f32x4)(0.f);

    int ra = w * 16 + ln;                // a-frag LDS row
#pragma unroll
    for (int ks = 0; ks < 4; ++ks) {
        int klo = (ks * 64 + kg * 8) ^ sw;
        int khi = (ks * 64 + 32 + kg * 8) ^ sw;
        frag af;
        {
            uint2 lo = *(const uint2*)((const char*)xs + ra * 256 + klo);
            uint2 hi = *(const uint2*)((const char*)xs + ra * 256 + khi);
            af.u[0] = lo.x; af.u[1] = lo.y; af.u[2] = hi.x; af.u[3] = hi.y;
        }
#pragma unroll
        for (int t = 0; t < 8; ++t) {
            int n = t * 16 + ln;
            frag bf;
            uint2 lo = *(const uint2*)((const char*)wsh + n * 256 + klo);
            uint2 hi = *(const uint2*)((const char*)wsh + n * 256 + khi);
            bf.u[0] = lo.x; bf.u[1] = lo.y; bf.u[2] = hi.x; bf.u[3] = hi.y;
            acc[t] = __builtin_amdgcn_mfma_f32_16x16x32_bf16(af.s, bf.s, acc[t], 0, 0, 0);
        }
    }

    float as8[8], ad8[8];
#pragma unroll
    for (int t = 0; t < 8; ++t) { as8[t] = a_src[t * 16 + ln]; ad8[t] = a_dst[t * 16 + ln]; }

#pragma unroll
    for (int r = 0; r < 4; ++r) {
        int m = m0 + w * 16 + kg * 4 + r;
        float ps = 0.f, pd = 0.f;
#pragma unroll
        for (int t = 0; t < 8; ++t) {
            float vv = acc[t][r];
            h[(size_t)m * FEAT + t * 16 + ln] = f2bf(vv);
            ps += vv * as8[t];
            pd += vv * ad8[t];
        }
#pragma unroll
        for (int off = 8; off >= 1; off >>= 1) {
            ps += __shfl_xor(ps, off);
            pd += __shfl_xor(pd, off);
        }
        if (ln == 0) { es[m] = ps; ed[m] = pd; }
    }
}

// ---------------------------------------------------------------------------
// K3: aggregate (unchanged): one wave per (b,i); reg-cached z/col; 8 nbrs/iter
// (4 groups x 2 chains), 8 bf16 cols/lane as uint4, packed-f32 FMA.
// blockIdx&7 = batch -> XCD/L2 affinity for the 1MB h[b] slice.
// ---------------------------------------------------------------------------
__global__ __launch_bounds__(256) void aggregate(const unsigned short* __restrict__ h,
                                                 const float* __restrict__ es,
                                                 const float* __restrict__ ed,
                                                 const unsigned short* __restrict__ nbr,
                                                 const int* __restrict__ deg,
                                                 const float* __restrict__ bias,
                                                 float* __restrict__ out) {
    int lane = threadIdx.x & 63;
    int g = lane >> 4;
    int c8 = (lane & 15) * 8;
    int b = blockIdx.x & 7;
    int i = (blockIdx.x >> 3) * 4 + (threadIdx.x >> 6);

    int d = deg[i];
    const unsigned short* lst = nbr + (size_t)i * CAP;
    float esv = es[b * N_NODES + i];
    const float* edb = ed + b * N_NODES;

    float zv0 = -1e30f, zv1 = -1e30f, zv2 = -1e30f, zv3 = -1e30f;
    int cv0 = 0, cv1 = 0, cv2 = 0, cv3 = 0;
    float m = -1e30f;
#define PASS1(c, zz, cc)                                            \
    if (c * 64 < d) {                                               \
        int j = c * 64 + lane;                                      \
        if (j < d) {                                                \
            cc = lst[j];                                            \
            float z0 = esv + edb[cc];                               \
            zz = z0 > 0.f ? z0 : 0.2f * z0;                         \
        }                                                           \
        m = fmaxf(m, zz);                                           \
    }
    PASS1(0, zv0, cv0)
    PASS1(1, zv1, cv1)
    PASS1(2, zv2, cv2)
    PASS1(3, zv3, cv3)
#undef PASS1
#pragma unroll
    for (int off = 32; off >= 1; off >>= 1) m = fmaxf(m, __shfl_xor(m, off));

    const unsigned short* hb = h + (size_t)b * N_NODES * FEAT;
    v2f acc0[4], acc1[4];
#pragma unroll
    for (int k = 0; k < 4; ++k) { acc0[k] = (v2f)(0.f); acc1[k] = (v2f)(0.f); }
    float s = 0.f;
#define PASS2(c, zz, cc)                                                        \
    if (c * 64 < d) {                                                           \
        float p = __expf(zz - m);                                               \
        s += p;                                                                 \
        int n = d - c * 64; if (n > 64) n = 64;                                 \
        int nn = (n + 7) & ~7;                                                  \
        for (int jj = 0; jj < nn; jj += 8) {                                    \
            int j0 = jj + g, j1 = jj + 4 + g;                                   \
            float p0 = __shfl(p, j0); int cj0 = __shfl(cc, j0);                 \
            float p1 = __shfl(p, j1); int cj1 = __shfl(cc, j1);                 \
            uint4 h0 = *(const uint4*)(hb + (size_t)cj0 * FEAT + c8);           \
            uint4 h1 = *(const uint4*)(hb + (size_t)cj1 * FEAT + c8);           \
            v2f pp0; pp0[0] = p0; pp0[1] = p0;                                  \
            v2f pp1; pp1[0] = p1; pp1[1] = p1;                                  \
            fma8v(acc0, pp0, h0);                                               \
            fma8v(acc1, pp1, h1);                                               \
        }                                                                       \
    }
    PASS2(0, zv0, cv0)
    PASS2(1, zv1, cv1)
    PASS2(2, zv2, cv2)
    PASS2(3, zv3, cv3)
#undef PASS2

#pragma unroll
    for (int off = 32; off >= 1; off >>= 1) s += __shfl_xor(s, off);
    float inv = 1.0f / s;

#pragma unroll
    for (int k = 0; k < 4; ++k) acc0[k] += acc1[k];
#pragma unroll
    for (int k = 0; k < 4; ++k) {
        acc0[k][0] += __shfl_xor(acc0[k][0], 16);
        acc0[k][1] += __shfl_xor(acc0[k][1], 16);
        acc0[k][0] += __shfl_xor(acc0[k][0], 32);
        acc0[k][1] += __shfl_xor(acc0[k][1], 32);
    }

    if (lane < 16) {
        float4 b0 = *(const float4*)(bias + c8);
        float4 b1 = *(const float4*)(bias + c8 + 4);
        float o[8];
        o[0] = acc0[0][0] * inv + b0.x; o[1] = acc0[0][1] * inv + b0.y;
        o[2] = acc0[1][0] * inv + b0.z; o[3] = acc0[1][1] * inv + b0.w;
        o[4] = acc0[2][0] * inv + b1.x; o[5] = acc0[2][1] * inv + b1.y;
        o[6] = acc0[3][0] * inv + b1.z; o[7] = acc0[3][1] * inv + b1.w;
#pragma unroll
        for (int k = 0; k < 8; ++k) o[k] = o[k] > 0.f ? o[k] : 0.3f * o[k];
        float* orow = out + ((size_t)b * N_NODES + i) * FEAT + c8;
        *(float4*)orow = make_float4(o[0], o[1], o[2], o[3]);
        *(float4*)(orow + 4) = make_float4(o[4], o[5], o[6], o[7]);
    }
}

// ---------------------------------------------------------------------------
extern "C" void kernel_launch(void* const* d_in, const int* in_sizes, int n_in,
                              void* d_out, int out_size, void* d_ws, size_t ws_size,
                              hipStream_t stream) {
    const float* x     = (const float*)d_in[0];
    const float* A     = (const float*)d_in[1];
    const float* W     = (const float*)d_in[2];
    const float* bias  = (const float*)d_in[3];
    const float* a_src = (const float*)d_in[4];
    const float* a_dst = (const float*)d_in[5];
    float* out = (float*)d_out;

    // workspace layout (~10.9 MB)
    char* ws = (char*)d_ws;
    unsigned short* h  = (unsigned short*)ws;                   // B*N*C bf16 (8.39 MB)
    float* es = (float*)(h + (size_t)BATCH * N_NODES * FEAT);   // B*N f32
    float* ed = es + BATCH * N_NODES;                           // B*N f32
    unsigned short* Wt = (unsigned short*)(ed + BATCH * N_NODES); // F*C bf16 (32 KB)
    int* dg = (int*)(Wt + FEAT * FEAT);                         // N ints
    unsigned short* nb = (unsigned short*)(dg + N_NODES);       // N*CAP (2 MB)

    hipLaunchKernelGGL(scan_k, dim3(N_NODES), dim3(512), 0, stream,
                       A, W, nb, dg, Wt);
    hipLaunchKernelGGL(gemm_mfma, dim3(BATCH * N_NODES / 64), dim3(256), 0, stream,
                       x, Wt, a_src, a_dst, h, es, ed);
    hipLaunchKernelGGL(aggregate, dim3(BATCH * N_NODES / 4), dim3(256), 0, stream,
                       h, es, ed, nb, dg, bias, out);
}